// Round 1
// baseline (605.154 us; speedup 1.0000x reference)
//
#include <hip/hip_runtime.h>
#include <cstdint>

#define NB 2
#define NH 16
#define NT 2048
#define ND 1024
#define DH 64

// ---------------------------------------------------------------------------
// Kernel 1: v = normalize(x rows per head), stored K-major: vT[b,h,d,t]
// grid = B*H*(T/256) = 256 blocks, 256 threads; coalesced writes (lane = t)
// ---------------------------------------------------------------------------
__global__ __launch_bounds__(256) void k_normalize(const float* __restrict__ x,
                                                   float* __restrict__ vT) {
    int bid = blockIdx.x;
    int tid = threadIdx.x;
    int chunk = bid & 7;          // T/256 = 8
    int h = (bid >> 3) & 15;
    int b = bid >> 7;
    int t = chunk * 256 + tid;

    const float* xr = x + ((size_t)(b * NT + t)) * ND + h * DH;
    float4 vv[16];
    float ss = 0.f;
#pragma unroll
    for (int i = 0; i < 16; ++i) {
        vv[i] = reinterpret_cast<const float4*>(xr)[i];
        ss += vv[i].x * vv[i].x + vv[i].y * vv[i].y + vv[i].z * vv[i].z + vv[i].w * vv[i].w;
    }
    float inv = 1.f / fmaxf(sqrtf(ss), 1e-12f);

    float* vb = vT + ((size_t)(b * NH + h)) * DH * NT + t;
#pragma unroll
    for (int i = 0; i < 16; ++i) {
        vb[(size_t)(4 * i + 0) * NT] = vv[i].x * inv;
        vb[(size_t)(4 * i + 1) * NT] = vv[i].y * inv;
        vb[(size_t)(4 * i + 2) * NT] = vv[i].z * inv;
        vb[(size_t)(4 * i + 3) * NT] = vv[i].w * inv;
    }
}

// ---------------------------------------------------------------------------
// Kernel 2: SvT[b,h,e,t] = sum_d S[d][e] * vT[b,h,d,t],  S = A - A^T per head
// grid = B*H*(T/64) = 1024 blocks, 256 threads; 4x4 microtile GEMM, K=64
// ---------------------------------------------------------------------------
__global__ __launch_bounds__(256) void k_sv(const float* __restrict__ A,
                                            const float* __restrict__ vT,
                                            float* __restrict__ SvT) {
    __shared__ float S[DH * DH];   // S[d][e], d-major (this IS the A-operand layout)
    __shared__ float Vs[DH * DH];  // Vs[d][t_local]
    int bid = blockIdx.x;
    int tid = threadIdx.x;
    int tc = bid & 31;             // T/64 = 32
    int h = (bid >> 5) & 15;
    int b = bid >> 9;

    const float* Ah = A + (size_t)h * DH * DH;
    for (int i = tid; i < DH * DH; i += 256) {
        int d = i >> 6, e = i & 63;
        S[i] = Ah[d * DH + e] - Ah[e * DH + d];
    }
    const float* vbase = vT + ((size_t)(b * NH + h)) * DH * NT + tc * DH;
#pragma unroll
    for (int r = 0; r < 4; ++r) {
        int f = tid + 256 * r;
        int k = f >> 4;
        int n = (f & 15) << 2;
        *reinterpret_cast<float4*>(&Vs[k * DH + n]) =
            *reinterpret_cast<const float4*>(&vbase[(size_t)k * NT + n]);
    }
    __syncthreads();

    int tx = tid & 15, ty = tid >> 4;
    float acc[4][4] = {};
#pragma unroll 8
    for (int k = 0; k < DH; ++k) {
        float4 a = reinterpret_cast<const float4*>(S)[k * 16 + ty];
        float4 bb = reinterpret_cast<const float4*>(Vs)[k * 16 + tx];
        float av[4] = {a.x, a.y, a.z, a.w};
        float bv[4] = {bb.x, bb.y, bb.z, bb.w};
#pragma unroll
        for (int i = 0; i < 4; ++i)
#pragma unroll
            for (int j = 0; j < 4; ++j)
                acc[i][j] = fmaf(av[i], bv[j], acc[i][j]);
    }

    float* svb = SvT + ((size_t)(b * NH + h)) * DH * NT + tc * DH;
#pragma unroll
    for (int i = 0; i < 4; ++i) {
        float4 o;
        o.x = acc[i][0]; o.y = acc[i][1]; o.z = acc[i][2]; o.w = acc[i][3];
        *reinterpret_cast<float4*>(&svb[(size_t)(ty * 4 + i) * NT + tx * 4]) = o;
    }
}

// ---------------------------------------------------------------------------
// Kernel 3: wedge[t][s] = sum_e SvT[e][t] * vT[e][s]   per (b,h)
// Skew-symmetric: wedge[s][t] = -wedge[t][s] -> compute only tm<=tn tile pairs
// (528 of 1024 per head), mirror-write -C^T via LDS transpose.
// grid = 32*528 blocks, 256 threads; 64x64 tile, K=64, 4x4 microtile.
// ---------------------------------------------------------------------------
__global__ __launch_bounds__(256) void k_wedge(const float* __restrict__ vT,
                                               const float* __restrict__ SvT,
                                               float* __restrict__ out) {
    __shared__ float smem[2 * DH * DH];  // As | Bs ; Cs (64x65) reuses after compute
    float* As = smem;
    float* Bs = smem + DH * DH;

    int tid = threadIdx.x;
    int bh = blockIdx.x / 528;
    int p = blockIdx.x % 528;
    int tm = 0;
    while (p >= 32 - tm) { p -= 32 - tm; tm++; }
    int tn = tm + p;

    const float* vb = vT + (size_t)bh * DH * NT;
    const float* svb = SvT + (size_t)bh * DH * NT;
    float* ob = out + (size_t)bh * NT * NT;

#pragma unroll
    for (int r = 0; r < 4; ++r) {
        int f = tid + 256 * r;
        int k = f >> 4;
        int c = (f & 15) << 2;
        *reinterpret_cast<float4*>(&As[k * DH + c]) =
            *reinterpret_cast<const float4*>(&svb[(size_t)k * NT + tm * DH + c]);
        *reinterpret_cast<float4*>(&Bs[k * DH + c]) =
            *reinterpret_cast<const float4*>(&vb[(size_t)k * NT + tn * DH + c]);
    }
    __syncthreads();

    int tx = tid & 15, ty = tid >> 4;
    float acc[4][4] = {};
#pragma unroll 8
    for (int k = 0; k < DH; ++k) {
        float4 a = reinterpret_cast<const float4*>(As)[k * 16 + ty];
        float4 bb = reinterpret_cast<const float4*>(Bs)[k * 16 + tx];
        float av[4] = {a.x, a.y, a.z, a.w};
        float bv[4] = {bb.x, bb.y, bb.z, bb.w};
#pragma unroll
        for (int i = 0; i < 4; ++i)
#pragma unroll
            for (int j = 0; j < 4; ++j)
                acc[i][j] = fmaf(av[i], bv[j], acc[i][j]);
    }

    // direct tile write: rows t = tm*64 + ty*4+i, cols s = tn*64 + tx*4..+3
#pragma unroll
    for (int i = 0; i < 4; ++i) {
        float4 o;
        o.x = acc[i][0]; o.y = acc[i][1]; o.z = acc[i][2]; o.w = acc[i][3];
        *reinterpret_cast<float4*>(
            &ob[(size_t)(tm * DH + ty * 4 + i) * NT + tn * DH + tx * 4]) = o;
    }

    if (tm != tn) {
        __syncthreads();               // everyone done reading As/Bs
        float* Cs = smem;              // [64][65] padded transpose buffer
#pragma unroll
        for (int i = 0; i < 4; ++i)
#pragma unroll
            for (int j = 0; j < 4; ++j)
                Cs[(ty * 4 + i) * 65 + tx * 4 + j] = acc[i][j];
        __syncthreads();
#pragma unroll
        for (int i = 0; i < 4; ++i) {
            int row2 = ty * 4 + i;     // local s index
            float4 o;
            o.x = -Cs[(tx * 4 + 0) * 65 + row2];
            o.y = -Cs[(tx * 4 + 1) * 65 + row2];
            o.z = -Cs[(tx * 4 + 2) * 65 + row2];
            o.w = -Cs[(tx * 4 + 3) * 65 + row2];
            *reinterpret_cast<float4*>(
                &ob[(size_t)(tn * DH + row2) * NT + tm * DH + tx * 4]) = o;
        }
    }
}

// ---------------------------------------------------------------------------
extern "C" void kernel_launch(void* const* d_in, const int* in_sizes, int n_in,
                              void* d_out, int out_size, void* d_ws, size_t ws_size,
                              hipStream_t stream) {
    const float* x = (const float*)d_in[0];
    const float* A = (const float*)d_in[1];
    float* out = (float*)d_out;

    // ws layout: vT [B,H,DH,T] then SvT [B,H,DH,T]; 2 * 16 MiB = 32 MiB needed
    float* vT = (float*)d_ws;
    float* SvT = vT + (size_t)NB * NH * DH * NT;

    k_normalize<<<NB * NH * (NT / 256), 256, 0, stream>>>(x, vT);
    k_sv<<<NB * NH * (NT / 64), 256, 0, stream>>>(A, vT, SvT);
    k_wedge<<<NB * NH * 528, 256, 0, stream>>>(vT, SvT, out);
}